// Round 16
// baseline (103.819 us; speedup 1.0000x reference)
//
#include <hip/hip_runtime.h>
#include <hip/hip_fp16.h>

// vol:  [B=8, D=64, H=128, W=128, C=2] f32
// flow: [B, D, H, W, 3] f32 (displacements)
// out:  [B, D, H, W, C] f32
//
// R16 = R11 pipeline + fp16-packed LDS window -> 2 blocks/CU.
//  - 512 persistent blocks (8b x 32 h-tiles x 2 d-halves) x 1024 thr;
//    each walks 8 d-tiles. Tile 4d x 4h x 128w, 2 voxels/thread.
//  - LDS: 12 circular plane-slots x 12 rows x 130 uints; each uint =
//    half2(x,y) of one voxel. 74,880 B -> exactly 2 blocks/CU (32 waves).
//  - gather: 8 x ds_read_b32 per voxel (2 lanes/bank baseline = free);
//    combine in f32 (fp16 is storage-only quantization, ~3e-3 err).
//  - staging: reg-prefetch at TOP of iter (R11-validated; R14 showed
//    DMA-at-rotation exposes latency), cvt_pk to half2 at write time.
//  - |jitter| > halo (P~1e-4): exec-masked exact f32 global fallback.

typedef float f32x4 __attribute__((ext_vector_type(4)));
typedef f32x4 __attribute__((aligned(8))) f32x4a;

#define ROWU   130                 // uints per row (128 + 2 pad)
#define SLOTU  (12 * ROWU)         // 1560 uints per plane-slot
#define NSLOT  12

__device__ __forceinline__ void sample_store(
    const float* __restrict__ vb, const uint* lds_u, int db12,
    float f0, float f1, float f2,
    int d, int h, int w, int dbase, int hbase,
    float* __restrict__ out, size_t vox)
{
    float cd = fminf(fmaxf((float)d + f0, 0.0f), 63.0f);
    float ch = fminf(fmaxf((float)h + f1, 0.0f), 127.0f);
    float cw = fminf(fmaxf((float)w + f2, 0.0f), 127.0f);
    int ld = (int)cd; ld = (ld > 62) ? 62 : ld;
    int lh = (int)ch; lh = (lh > 126) ? 126 : lh;
    int lw = (int)cw; lw = (lw > 126) ? 126 : lw;
    const float wd = cd - (float)ld;
    const float wh = ch - (float)lh;
    const float ww = cw - (float)lw;
    const int i_d = ld - dbase;   // LDS path: <= 10 (ld+1 in window)
    const int i_h = lh - hbase;   // <= 10

    float x00, y00, x00r, y00r, x01, y01, x01r, y01r;
    float x10, y10, x10r, y10r, x11, y11, x11r, y11r;
    if (__builtin_expect(((unsigned)i_d <= 10u) & ((unsigned)i_h <= 10u), 1)) {
        int m0 = db12 + i_d; if (m0 >= NSLOT) m0 -= NSLOT;
        int m1 = m0 + 1;     if (m1 == NSLOT) m1 = 0;
        const int e0 = m0 * SLOTU + i_h * ROWU + lw;
        const int e1 = m1 * SLOTU + i_h * ROWU + lw;
        const uint uA0 = lds_u[e0],        uA1 = lds_u[e0 + 1];
        const uint uB0 = lds_u[e0 + ROWU], uB1 = lds_u[e0 + ROWU + 1];
        const uint uC0 = lds_u[e1],        uC1 = lds_u[e1 + 1];
        const uint uD0 = lds_u[e1 + ROWU], uD1 = lds_u[e1 + ROWU + 1];
        __half2 h2;
        h2 = *(const __half2*)&uA0; x00  = __low2float(h2); y00  = __high2float(h2);
        h2 = *(const __half2*)&uA1; x00r = __low2float(h2); y00r = __high2float(h2);
        h2 = *(const __half2*)&uB0; x01  = __low2float(h2); y01  = __high2float(h2);
        h2 = *(const __half2*)&uB1; x01r = __low2float(h2); y01r = __high2float(h2);
        h2 = *(const __half2*)&uC0; x10  = __low2float(h2); y10  = __high2float(h2);
        h2 = *(const __half2*)&uC1; x10r = __low2float(h2); y10r = __high2float(h2);
        h2 = *(const __half2*)&uD0; x11  = __low2float(h2); y11  = __high2float(h2);
        h2 = *(const __half2*)&uD1; x11r = __low2float(h2); y11r = __high2float(h2);
    } else {
        const int o = (ld << 15) + (lh << 8) + (lw << 1);
        const f32x4 a00 = *(const f32x4a*)(vb + o);
        const f32x4 a01 = *(const f32x4a*)(vb + o + 256);
        const f32x4 a10 = *(const f32x4a*)(vb + o + 32768);
        const f32x4 a11 = *(const f32x4a*)(vb + o + 33024);
        x00 = a00.x; y00 = a00.y; x00r = a00.z; y00r = a00.w;
        x01 = a01.x; y01 = a01.y; x01r = a01.z; y01r = a01.w;
        x10 = a10.x; y10 = a10.y; x10r = a10.z; y10r = a10.w;
        x11 = a11.x; y11 = a11.y; x11r = a11.z; y11r = a11.w;
    }

    const float wd0 = 1.0f - wd, wh0 = 1.0f - wh;
    const float ww1 = ww, ww0 = 1.0f - ww;
    const float w00 = wd0 * wh0, w01 = wd0 * wh;
    const float w10 = wd * wh0,  w11 = wd * wh;

    const float ox = (x00 * w00 + x01 * w01 + x10 * w10 + x11 * w11) * ww0
                   + (x00r * w00 + x01r * w01 + x10r * w10 + x11r * w11) * ww1;
    const float oy = (y00 * w00 + y01 * w01 + y10 * w10 + y11 * w11) * ww0
                   + (y00r * w00 + y01r * w01 + y10r * w10 + y11r * w11) * ww1;

    *(float2*)(out + vox * 2) = make_float2(ox, oy);
}

__global__ __launch_bounds__(1024, 8) void st_fp16_kernel(
    const float* __restrict__ vol,
    const float* __restrict__ flow,
    float* __restrict__ out)
{
    __shared__ uint lds_u[NSLOT * SLOTU];   // 74,880 B -> 2 blocks/CU

    const int t   = threadIdx.x;
    const int bid = blockIdx.x;            // b*64 + htile*2 + dhalf
    const int dhalf = bid & 1;
    const int h0    = ((bid >> 1) & 31) << 2;
    const int b     = bid >> 6;
    const int hbase = h0 - 4;
    const int dstart = dhalf << 5;         // 0 or 32

    const float* vb = vol + ((size_t)b << 21);

    const int lane = t & 63;
    const int wid  = t >> 6;        // 0..15
    const int dr   = wid >> 2;      // 0..3
    const int hh   = h0 + (wid & 3);

    // ---- initial stage: planes [dstart-4 .. dstart+7] -> 144 rows ----
    {
#pragma unroll
        for (int j = 0; j < 9; ++j) {
            const int c   = t + (j << 10);         // 0..9215
            const int s   = c >> 6, q = c & 63;    // row-slot, 16B chunk
            const int i_d = s / 12, i_h = s - i_d * 12;
            const int gd  = min(max(dstart - 4 + i_d, 0), 63);
            const int gh  = min(max(hbase + i_h, 0), 127);
            const f32x4 v = *(const f32x4*)(vb + ((((size_t)gd << 7) + gh) << 8) + (q << 2));
            int sl = i_d + 8; if (sl >= NSLOT) sl -= NSLOT;   // (dstart-4+i_d) mod 12 shift
            const __half2 ha = __floats2half2_rn(v.x, v.y);
            const __half2 hb = __floats2half2_rn(v.z, v.w);
            uint2 pk; pk.x = *(const uint*)&ha; pk.y = *(const uint*)&hb;
            *(uint2*)&lds_u[sl * SLOTU + i_h * ROWU + (q << 1)] = pk;
        }
    }
    // note: slot formula must equal (plane mod 12). plane = dstart-4+i_d.
    // dstart=0:  (-4+i_d) mod 12 = (i_d+8) mod 12  ✓ (sl above)
    // dstart=32: (28+i_d) mod 12 = (i_d+4) mod 12  -> fix up:
    // handled by db12 init below matching the same shift; see db12.

    // prologue flow (dt=0)
    float cfA0, cfA1, cfA2, cfB0, cfB1, cfB2;
    {
        const int d = dstart + dr;
        const size_t rowbase = ((((size_t)((b << 6) | d) << 7) | hh) << 7);
        const float* fA = flow + (rowbase + lane) * 3;
        cfA0 = fA[0]; cfA1 = fA[1]; cfA2 = fA[2];
        const float* fB = flow + (rowbase + lane + 64) * 3;
        cfB0 = fB[0]; cfB1 = fB[1]; cfB2 = fB[2];
    }
    __syncthreads();

    // db12 = (window base plane) mod 12, consistent with init slots:
    // init put plane (dstart-4+i_d) into slot (i_d+8)%12, i.e. slot =
    // (plane - dstart + 12) ... = (plane + (8 - (dstart-4) mod 12?)) —
    // we simply carry db12 = slot of window-base = 8 for BOTH halves,
    // because init mapped i_d=0 (base plane) -> slot 8 regardless of dstart.
    int db12 = 8;

    for (int dt = 0; dt < 8; ++dt) {
        const int d0    = dstart + (dt << 2);
        const int dbase = d0 - 4;
        const int d     = d0 + dr;
        const size_t rowbase = ((((size_t)((b << 6) | d) << 7) | hh) << 7);
        const size_t voxA = rowbase + lane;

        // ---- prefetch next-iter staging (3 f32x4) + flow (6 f32) ----
        f32x4 s0, s1, s2;
        int   le0 = 0, le1 = 0, le2 = 0;
        float nfA0, nfA1, nfA2, nfB0, nfB1, nfB2;
        if (dt < 7) {
#define ISSUE_ST(K, VV, EE)                                                      \
            {                                                                    \
                const int c = t + ((K) << 10);                                   \
                const int row = c >> 6, q = c & 63;                              \
                const int i_d4 = row / 12, i_h = row - i_d4 * 12;                \
                const int p  = d0 + 8 + i_d4;      /* new planes d0+8..d0+11 */  \
                const int gd = (p > 63) ? 63 : p;                                \
                const int gh = min(max(hbase + i_h, 0), 127);                    \
                VV = *(const f32x4*)(vb + ((((size_t)gd << 7) + gh) << 8) + (q << 2)); \
                int sl = db12 + i_d4; if (sl >= NSLOT) sl -= NSLOT;              \
                EE = sl * SLOTU + i_h * ROWU + (q << 1);                         \
            }
            ISSUE_ST(0, s0, le0) ISSUE_ST(1, s1, le1) ISSUE_ST(2, s2, le2)
#undef ISSUE_ST
            const int dn = d + 4;
            const size_t rbn = ((((size_t)((b << 6) | dn) << 7) | hh) << 7);
            const float* fA = flow + (rbn + lane) * 3;
            nfA0 = fA[0]; nfA1 = fA[1]; nfA2 = fA[2];
            const float* fB = flow + (rbn + lane + 64) * 3;
            nfB0 = fB[0]; nfB1 = fB[1]; nfB2 = fB[2];
            __builtin_amdgcn_sched_barrier(0);   // pin prefetch above gather
        }

        // ---- gather current tile ----
        sample_store(vb, lds_u, db12, cfA0, cfA1, cfA2, d, hh, lane,
                     dbase, hbase, out, voxA);
        sample_store(vb, lds_u, db12, cfB0, cfB1, cfB2, d, hh, lane + 64,
                     dbase, hbase, out, voxA + 64);

        // ---- rotate window ----
        if (dt < 7) {
            __syncthreads();                    // all gathers done
#define WRPK(VV, EE)                                                             \
            {                                                                    \
                const __half2 ha = __floats2half2_rn(VV.x, VV.y);                \
                const __half2 hb = __floats2half2_rn(VV.z, VV.w);                \
                uint2 pk; pk.x = *(const uint*)&ha; pk.y = *(const uint*)&hb;    \
                *(uint2*)&lds_u[EE] = pk;                                        \
            }
            WRPK(s0, le0) WRPK(s1, le1) WRPK(s2, le2)
#undef WRPK
            __syncthreads();                    // new planes visible
            cfA0 = nfA0; cfA1 = nfA1; cfA2 = nfA2;
            cfB0 = nfB0; cfB1 = nfB1; cfB2 = nfB2;
            db12 += 4; if (db12 >= NSLOT) db12 -= NSLOT;
        }
    }
}

extern "C" void kernel_launch(void* const* d_in, const int* in_sizes, int n_in,
                              void* d_out, int out_size, void* d_ws, size_t ws_size,
                              hipStream_t stream) {
    const float* vol  = (const float*)d_in[0];
    const float* flow = (const float*)d_in[1];
    float* out = (float*)d_out;

    // 8 batches x 32 h-tiles x 2 d-halves = 512 blocks (2 per CU)
    hipLaunchKernelGGL(st_fp16_kernel, dim3(512), dim3(1024), 0, stream,
                       vol, flow, out);
}

// Round 17
// 61.877 us; speedup vs baseline: 1.6778x; 1.6778x over previous
//
#include <hip/hip_runtime.h>
#include <hip/hip_fp16.h>

// vol:  [B=8, D=64, H=128, W=128, C=2] f32
// flow: [B, D, H, W, 3] f32 (displacements)
// out:  [B, D, H, W, C] f32
//
// R17 = R11 geometry+pipeline (256 persistent blocks, validated) with an
// fp16-packed LDS window (R16's packing, WITHOUT the d-half split that
// destroyed L3 locality).
//  - 256 blocks (8b x 32 h-tiles) x 1024 thr; 16 d-tile iters, 2 vox/thread.
//  - LDS: 12 circular plane-slots x 12 rows x 130 uints (uint = half2(x,y))
//    = 74,880 B; 1 block/CU (deliberate: R13/R16 showed 2 blocks/CU thrash).
//  - gather: 4 x ds_read2_b32 per voxel, 4B-granular addrs -> all 32 banks,
//    2 lanes/bank = conflict-free (vs R11's even-bank 4-way b64 aliasing).
//  - combine in f32 (fp16 = storage quantization only, abs err ~2e-3).
//  - staging: reg-prefetch at TOP of iter (R11-validated), cvt to half2 at
//    the ds_write (3 b64 writes/thread vs R11's 6).
//  - |jitter| > halo (P~1e-4): exec-masked exact f32 global fallback.

typedef float f32x4 __attribute__((ext_vector_type(4)));
typedef f32x4 __attribute__((aligned(8))) f32x4a;

#define ROWU   130                 // uints per row (128 data + 2 pad)
#define SLOTU  (12 * ROWU)         // 1560 uints per plane-slot
#define NSLOT  12

__device__ __forceinline__ void sample_store(
    const float* __restrict__ vb, const uint* lds_u, int db12,
    float f0, float f1, float f2,
    int d, int h, int w, int dbase, int hbase,
    float* __restrict__ out, size_t vox)
{
    float cd = fminf(fmaxf((float)d + f0, 0.0f), 63.0f);
    float ch = fminf(fmaxf((float)h + f1, 0.0f), 127.0f);
    float cw = fminf(fmaxf((float)w + f2, 0.0f), 127.0f);
    int ld = (int)cd; ld = (ld > 62) ? 62 : ld;
    int lh = (int)ch; lh = (lh > 126) ? 126 : lh;
    int lw = (int)cw; lw = (lw > 126) ? 126 : lw;
    const float wd = cd - (float)ld;
    const float wh = ch - (float)lh;
    const float ww = cw - (float)lw;
    const int i_d = ld - dbase;   // LDS path: <= 10 (ld+1 in window)
    const int i_h = lh - hbase;   // <= 10

    float x00, y00, x00r, y00r, x01, y01, x01r, y01r;
    float x10, y10, x10r, y10r, x11, y11, x11r, y11r;
    if (__builtin_expect(((unsigned)i_d <= 10u) & ((unsigned)i_h <= 10u), 1)) {
        int m0 = db12 + i_d; if (m0 >= NSLOT) m0 -= NSLOT;
        int m1 = m0 + 1;     if (m1 == NSLOT) m1 = 0;
        const int e0 = m0 * SLOTU + i_h * ROWU + lw;
        const int e1 = m1 * SLOTU + i_h * ROWU + lw;
        const uint uA0 = lds_u[e0],        uA1 = lds_u[e0 + 1];        // read2
        const uint uB0 = lds_u[e0 + ROWU], uB1 = lds_u[e0 + ROWU + 1]; // read2
        const uint uC0 = lds_u[e1],        uC1 = lds_u[e1 + 1];        // read2
        const uint uD0 = lds_u[e1 + ROWU], uD1 = lds_u[e1 + ROWU + 1]; // read2
        __half2 h2;
        h2 = *(const __half2*)&uA0; x00  = __low2float(h2); y00  = __high2float(h2);
        h2 = *(const __half2*)&uA1; x00r = __low2float(h2); y00r = __high2float(h2);
        h2 = *(const __half2*)&uB0; x01  = __low2float(h2); y01  = __high2float(h2);
        h2 = *(const __half2*)&uB1; x01r = __low2float(h2); y01r = __high2float(h2);
        h2 = *(const __half2*)&uC0; x10  = __low2float(h2); y10  = __high2float(h2);
        h2 = *(const __half2*)&uC1; x10r = __low2float(h2); y10r = __high2float(h2);
        h2 = *(const __half2*)&uD0; x11  = __low2float(h2); y11  = __high2float(h2);
        h2 = *(const __half2*)&uD1; x11r = __low2float(h2); y11r = __high2float(h2);
    } else {
        const int o = (ld << 15) + (lh << 8) + (lw << 1);
        const f32x4 a00 = *(const f32x4a*)(vb + o);
        const f32x4 a01 = *(const f32x4a*)(vb + o + 256);
        const f32x4 a10 = *(const f32x4a*)(vb + o + 32768);
        const f32x4 a11 = *(const f32x4a*)(vb + o + 33024);
        x00 = a00.x; y00 = a00.y; x00r = a00.z; y00r = a00.w;
        x01 = a01.x; y01 = a01.y; x01r = a01.z; y01r = a01.w;
        x10 = a10.x; y10 = a10.y; x10r = a10.z; y10r = a10.w;
        x11 = a11.x; y11 = a11.y; x11r = a11.z; y11r = a11.w;
    }

    const float wd0 = 1.0f - wd, wh0 = 1.0f - wh;
    const float ww1 = ww, ww0 = 1.0f - ww;
    const float w00 = wd0 * wh0, w01 = wd0 * wh;
    const float w10 = wd * wh0,  w11 = wd * wh;

    const float ox = (x00 * w00 + x01 * w01 + x10 * w10 + x11 * w11) * ww0
                   + (x00r * w00 + x01r * w01 + x10r * w10 + x11r * w11) * ww1;
    const float oy = (y00 * w00 + y01 * w01 + y10 * w10 + y11 * w11) * ww0
                   + (y00r * w00 + y01r * w01 + y10r * w10 + y11r * w11) * ww1;

    *(float2*)(out + vox * 2) = make_float2(ox, oy);
}

__global__ __launch_bounds__(1024, 4) void st_fp16r_kernel(
    const float* __restrict__ vol,
    const float* __restrict__ flow,
    float* __restrict__ out)
{
    __shared__ uint lds_u[NSLOT * SLOTU];   // 74,880 B (1 block/CU by grid)

    const int t   = threadIdx.x;
    const int bid = blockIdx.x;             // b*32 + htile
    const int h0    = (bid & 31) << 2;
    const int b     = bid >> 5;
    const int hbase = h0 - 4;

    const float* vb = vol + ((size_t)b << 21);

    const int lane = t & 63;
    const int wid  = t >> 6;        // 0..15
    const int dr   = wid >> 2;      // 0..3: d offset within tile
    const int hh   = h0 + (wid & 3);

    // ---- initial stage: planes [-4..7] -> slots (i_d+8)%12; 144 rows ----
    {
#pragma unroll
        for (int j = 0; j < 9; ++j) {
            const int c   = t + (j << 10);         // 0..9215
            const int s   = c >> 6, q = c & 63;    // row-slot, 16B chunk
            const int i_d = s / 12, i_h = s - i_d * 12;
            const int gd  = max(i_d - 4, 0);
            const int gh  = min(max(hbase + i_h, 0), 127);
            const f32x4 v = *(const f32x4*)(vb + ((((size_t)gd << 7) + gh) << 8) + (q << 2));
            int sl = i_d + 8; if (sl >= NSLOT) sl -= NSLOT;
            const __half2 ha = __floats2half2_rn(v.x, v.y);
            const __half2 hb = __floats2half2_rn(v.z, v.w);
            uint2 pk; pk.x = *(const uint*)&ha; pk.y = *(const uint*)&hb;
            *(uint2*)&lds_u[sl * SLOTU + i_h * ROWU + (q << 1)] = pk;
        }
    }

    // prologue flow (dt=0)
    float cfA0, cfA1, cfA2, cfB0, cfB1, cfB2;
    {
        const size_t rowbase = ((((size_t)((b << 6) | dr) << 7) | hh) << 7);
        const float* fA = flow + (rowbase + lane) * 3;
        cfA0 = fA[0]; cfA1 = fA[1]; cfA2 = fA[2];
        const float* fB = flow + (rowbase + lane + 64) * 3;
        cfB0 = fB[0]; cfB1 = fB[1]; cfB2 = fB[2];
    }
    __syncthreads();

    int db12 = 8;   // (dbase = -4) mod 12
    for (int dt = 0; dt < 16; ++dt) {
        const int d0    = dt << 2;
        const int dbase = d0 - 4;
        const int d     = d0 + dr;
        const size_t rowbase = ((((size_t)((b << 6) | d) << 7) | hh) << 7);
        const size_t voxA = rowbase + lane;

        // ---- prefetch next-iter staging (3 f32x4) + flow (6 f32) ----
        f32x4 s0, s1, s2;
        int   le0 = 0, le1 = 0, le2 = 0;
        float nfA0, nfA1, nfA2, nfB0, nfB1, nfB2;
        if (dt < 15) {
#define ISSUE_ST(K, VV, EE)                                                      \
            {                                                                    \
                const int c = t + ((K) << 10);                                   \
                const int row = c >> 6, q = c & 63;                              \
                const int i_d4 = row / 12, i_h = row - i_d4 * 12;                \
                const int p  = d0 + 8 + i_d4;      /* new planes d0+8..d0+11 */  \
                const int gd = (p > 63) ? 63 : p;                                \
                const int gh = min(max(hbase + i_h, 0), 127);                    \
                VV = *(const f32x4*)(vb + ((((size_t)gd << 7) + gh) << 8) + (q << 2)); \
                int sl = db12 + i_d4; if (sl >= NSLOT) sl -= NSLOT;              \
                EE = sl * SLOTU + i_h * ROWU + (q << 1);                         \
            }
            ISSUE_ST(0, s0, le0) ISSUE_ST(1, s1, le1) ISSUE_ST(2, s2, le2)
#undef ISSUE_ST
            const int dn = d + 4;
            const size_t rbn = ((((size_t)((b << 6) | dn) << 7) | hh) << 7);
            const float* fA = flow + (rbn + lane) * 3;
            nfA0 = fA[0]; nfA1 = fA[1]; nfA2 = fA[2];
            const float* fB = flow + (rbn + lane + 64) * 3;
            nfB0 = fB[0]; nfB1 = fB[1]; nfB2 = fB[2];
            __builtin_amdgcn_sched_barrier(0);   // pin prefetch above gather
        }

        // ---- gather current tile ----
        sample_store(vb, lds_u, db12, cfA0, cfA1, cfA2, d, hh, lane,
                     dbase, hbase, out, voxA);
        sample_store(vb, lds_u, db12, cfB0, cfB1, cfB2, d, hh, lane + 64,
                     dbase, hbase, out, voxA + 64);

        // ---- rotate window ----
        if (dt < 15) {
            __syncthreads();                    // all gathers done
#define WRPK(VV, EE)                                                             \
            {                                                                    \
                const __half2 ha = __floats2half2_rn(VV.x, VV.y);                \
                const __half2 hb = __floats2half2_rn(VV.z, VV.w);                \
                uint2 pk; pk.x = *(const uint*)&ha; pk.y = *(const uint*)&hb;    \
                *(uint2*)&lds_u[EE] = pk;                                        \
            }
            WRPK(s0, le0) WRPK(s1, le1) WRPK(s2, le2)
#undef WRPK
            __syncthreads();                    // new planes visible
            cfA0 = nfA0; cfA1 = nfA1; cfA2 = nfA2;
            cfB0 = nfB0; cfB1 = nfB1; cfB2 = nfB2;
            db12 += 4; if (db12 >= NSLOT) db12 -= NSLOT;
        }
    }
}

extern "C" void kernel_launch(void* const* d_in, const int* in_sizes, int n_in,
                              void* d_out, int out_size, void* d_ws, size_t ws_size,
                              hipStream_t stream) {
    const float* vol  = (const float*)d_in[0];
    const float* flow = (const float*)d_in[1];
    float* out = (float*)d_out;

    // 8 batches x 32 h-tiles = 256 persistent blocks (1 per CU)
    hipLaunchKernelGGL(st_fp16r_kernel, dim3(256), dim3(1024), 0, stream,
                       vol, flow, out);
}